// Round 5
// baseline (40.854 us; speedup 1.0000x reference)
//
#include <hip/hip_runtime.h>
#include <hip/hip_bf16.h>

typedef __bf16 bf16x8 __attribute__((ext_vector_type(8)));
typedef float  f32x4  __attribute__((ext_vector_type(4)));

#define NFEAT 128
#define NSAMP 8192
#define MT 8          // 8 M-tiles of 16 samples = 128 samples per wave

union BF8 { bf16x8 v; unsigned int u[4]; };

__device__ __forceinline__ unsigned int pk2(float lo, float hi) {
  float2 t; t.x = lo; t.y = hi;
  __hip_bfloat162 b = __float22bfloat162_rn(t);   // v_cvt_pk_bf16_f32
  union { __hip_bfloat162 b2; unsigned int u; } c;
  c.b2 = b;
  return c.u;
}

// Fragment layout (mfma_f32_16x16x32_bf16), verified rounds 1-4:
//   A: lane l holds A[row = l&15][kslot = 8*(l>>4) + j], j = 0..7
//   B: lane l holds B[kslot = 8*(l>>4) + j][col = l&15]
//   D: lane l reg r holds D[row = 4*(l>>4) + r][col = l&15]
// K-permutation pi(ks,g,j) = 32*ks + 16*(j>>2) + 4*g + (j&3) lets D-layout
// values (row = 16*mt + 4*g + r) feed the next layer's B-fragment in-lane.

// ---------------------------------------------------------------------------
// Prep: blocks 0..383 pack W1^T / W2^T fragments (pi-K, one bf16x8 per
// thread); blocks 384..511 transpose X -> Xt[f][n] via LDS tiles.
// ---------------------------------------------------------------------------
__global__ __launch_bounds__(256) void nam_prep(
    const float* __restrict__ X,  const float* __restrict__ W1,
    const float* __restrict__ W2, __bf16* __restrict__ W1p,
    __bf16* __restrict__ W2p, float* __restrict__ Xt) {
  __shared__ float lds[64][132];       // padded: float4-aligned rows
  const int tid = threadIdx.x;
  if (blockIdx.x < 384) {
    int w = blockIdx.x * 256 + tid;    // fragment index
    if (w < 65536) {                   // W1 fragments
      int f = w >> 9, q = (w >> 6) & 7, l = w & 63;
      int lg = l >> 4, ls = l & 15, mt = q >> 1, ks = q & 1;
      const float* base = W1 + f * 4096 + 16 * mt + ls;
      bf16x8 v;
#pragma unroll
      for (int j = 0; j < 8; ++j) {
        int i1 = 32 * ks + 16 * (j >> 2) + 4 * lg + (j & 3);
        v[j] = (__bf16)base[i1 * 64];
      }
      ((bf16x8*)W1p)[w] = v;
    } else {                           // W2 fragments
      int w2 = w - 65536;
      int f = w2 >> 8, q = (w2 >> 6) & 3, l = w2 & 63;
      int lg = l >> 4, ls = l & 15, mt = q >> 1, ks = q & 1;
      const float* base = W2 + f * 2048 + 16 * mt + ls;
      bf16x8 v;
#pragma unroll
      for (int j = 0; j < 8; ++j) {
        int i2 = 32 * ks + 16 * (j >> 2) + 4 * lg + (j & 3);
        v[j] = (__bf16)base[i2 * 32];
      }
      ((bf16x8*)W2p)[w2] = v;
    }
  } else {
    // transpose 64 samples x 128 features per block
    const int n0 = (blockIdx.x - 384) * 64;
#pragma unroll
    for (int it = 0; it < 8; ++it) {
      int idx = tid + 256 * it;        // 2048 float4 loads
      int r = idx >> 5, c4 = idx & 31;
      f32x4 v = *(const f32x4*)(X + (size_t)(n0 + r) * NFEAT + c4 * 4);
      *(f32x4*)&lds[r][c4 * 4] = v;
    }
    __syncthreads();
#pragma unroll
    for (int it = 0; it < 8; ++it) {
      int idx = tid + 256 * it;        // 2048 float4 stores
      int f = idx >> 4, s4 = idx & 15;
      f32x4 v;
#pragma unroll
      for (int k = 0; k < 4; ++k) v[k] = lds[s4 * 4 + k][f];
      *(f32x4*)(Xt + (size_t)f * NSAMP + n0 + s4 * 4) = v;
    }
  }
}

// ---------------------------------------------------------------------------
// Main: 256-thread block = 4 waves; one feature x 512 samples per block.
// Coalesced fragment loads, imm-offset Xt loads, packed bf16 converts.
// ---------------------------------------------------------------------------
__global__ __launch_bounds__(256) void nam_main(
    const float* __restrict__ Xt, const float* __restrict__ W0,
    const float* __restrict__ b0, const float* __restrict__ b1,
    const float* __restrict__ b2, const float* __restrict__ W3,
    const float* __restrict__ b3, const bf16x8* __restrict__ W1p,
    const bf16x8* __restrict__ W2p, float* __restrict__ part) {
  const int tid = threadIdx.x;
  const int l  = tid & 63;
  const int w  = tid >> 6;
  const int lg = l >> 4, ls = l & 15;
  const int f  = blockIdx.x >> 4;
  const int cg = blockIdx.x & 15;
  const int n0 = (cg * 4 + w) * 128;

  // ---- weight fragments: coalesced dwordx4 loads ----
  bf16x8 w1f[8], w2f[4];
#pragma unroll
  for (int q = 0; q < 8; ++q) w1f[q] = W1p[(f * 8 + q) * 64 + l];
#pragma unroll
  for (int q = 0; q < 4; ++q) w2f[q] = W2p[(f * 4 + q) * 64 + l];
  // ---- per-lane layer-1 weights (pi-indexed) ----
  float w0p[16], b0p[16];
#pragma unroll
  for (int ks = 0; ks < 2; ++ks)
#pragma unroll
    for (int j = 0; j < 8; ++j) {
      int kp = 32 * ks + 16 * (j >> 2) + 4 * lg + (j & 3);
      w0p[ks * 8 + j] = W0[f * 64 + kp];
      b0p[ks * 8 + j] = b0[f * 64 + kp];
    }
  f32x4 b1f[4], b2f[2], w3f[2];
#pragma unroll
  for (int mt = 0; mt < 4; ++mt)
    b1f[mt] = *(const f32x4*)(b1 + f * 64 + 16 * mt + 4 * lg);
#pragma unroll
  for (int mt = 0; mt < 2; ++mt)
    b2f[mt] = *(const f32x4*)(b2 + f * 32 + 16 * mt + 4 * lg);
#pragma unroll
  for (int mt = 0; mt < 2; ++mt)
    w3f[mt] = *(const f32x4*)(W3 + f * 32 + 16 * mt + 4 * lg);
  const float b3v = b3[f];

  const float* xb = Xt + (size_t)f * NSAMP + n0 + ls;   // one base + imm offsets
  float acc[MT];
#pragma unroll
  for (int m = 0; m < MT; ++m) acc[m] = 0.f;

#pragma unroll
  for (int m = 0; m < MT; ++m) {
    const float xv = xb[16 * m];
    // ---- layer 1 (VALU) + packed cvt -> L2 B-fragments ----
    BF8 a1[2];
#pragma unroll
    for (int ks = 0; ks < 2; ++ks) {
      float h[8];
#pragma unroll
      for (int j = 0; j < 8; ++j)
        h[j] = fmaxf(fmaf(xv, w0p[ks * 8 + j], b0p[ks * 8 + j]), 0.f);
#pragma unroll
      for (int p = 0; p < 4; ++p)
        a1[ks].u[p] = pk2(h[2 * p], h[2 * p + 1]);
    }
    // ---- layer 2: D[out2][sample], C-init = b1 ----
    f32x4 h2[4];
#pragma unroll
    for (int mt = 0; mt < 4; ++mt) {
      f32x4 c = b1f[mt];
      c = __builtin_amdgcn_mfma_f32_16x16x32_bf16(w1f[mt * 2 + 0], a1[0].v, c, 0, 0, 0);
      c = __builtin_amdgcn_mfma_f32_16x16x32_bf16(w1f[mt * 2 + 1], a1[1].v, c, 0, 0, 0);
      h2[mt] = c;
    }
    // ---- relu + packed cvt: h2 -> L3 B-fragments (pi K) ----
    BF8 bfr[2];
#pragma unroll
    for (int ks = 0; ks < 2; ++ks)
#pragma unroll
      for (int p = 0; p < 4; ++p) {
        float lo = fmaxf(h2[2 * ks + (p >> 1)][(p & 1) * 2 + 0], 0.f);
        float hi = fmaxf(h2[2 * ks + (p >> 1)][(p & 1) * 2 + 1], 0.f);
        bfr[ks].u[p] = pk2(lo, hi);
      }
    // ---- layer 3: D[out3][sample], C-init = b2 ----
    f32x4 h3[2];
#pragma unroll
    for (int mt = 0; mt < 2; ++mt) {
      f32x4 c = b2f[mt];
      c = __builtin_amdgcn_mfma_f32_16x16x32_bf16(w2f[mt * 2 + 0], bfr[0].v, c, 0, 0, 0);
      c = __builtin_amdgcn_mfma_f32_16x16x32_bf16(w2f[mt * 2 + 1], bfr[1].v, c, 0, 0, 0);
      h3[mt] = c;
    }
    // ---- epilogue: relu, dot with w3 (two chains) ----
    float p0 = (lg == 0) ? b3v : 0.f, p1 = 0.f;
#pragma unroll
    for (int r = 0; r < 4; ++r) {
      p0 = fmaf(fmaxf(h3[0][r], 0.f), w3f[0][r], p0);
      p1 = fmaf(fmaxf(h3[1][r], 0.f), w3f[1][r], p1);
    }
    acc[m] += p0 + p1;
  }
  // ---- reduce partials across the 4 lane-groups, store ----
#pragma unroll
  for (int m = 0; m < MT; ++m) {
    float v = acc[m];
    v += __shfl_xor(v, 16, 64);
    v += __shfl_xor(v, 32, 64);
    if (l < 16) part[f * NSAMP + n0 + 16 * m + l] = v;
  }
}

// ---------------------------------------------------------------------------
// Reduce: out[n] = bias + sum_f part[f][n]. Fixed order -> deterministic.
// ---------------------------------------------------------------------------
__global__ __launch_bounds__(256) void nam_reduce(const float* __restrict__ part,
                                                  const float* __restrict__ bias,
                                                  float* __restrict__ out) {
  int tid = threadIdx.x;
  int quad = blockIdx.x * 64 + (tid & 63);
  int gs = tid >> 6;
  f32x4 s = {0.f, 0.f, 0.f, 0.f};
#pragma unroll
  for (int g = gs * 32; g < gs * 32 + 32; ++g)
    s += *(const f32x4*)(part + (size_t)g * NSAMP + quad * 4);
  __shared__ f32x4 red[256];
  red[tid] = s;
  __syncthreads();
  if (gs == 0) {
    f32x4 t = red[tid] + red[tid + 64] + red[tid + 128] + red[tid + 192];
    float bv = bias[0];
    t[0] += bv; t[1] += bv; t[2] += bv; t[3] += bv;
    *(f32x4*)(out + quad * 4) = t;
  }
}

// ---------------------------------------------------------------------------
// Fallback (only if ws too small): naive fp32, correct but slow.
// ---------------------------------------------------------------------------
__global__ void nam_naive(const float* __restrict__ X, const float* __restrict__ W0,
                          const float* __restrict__ b0, const float* __restrict__ W1,
                          const float* __restrict__ b1, const float* __restrict__ W2,
                          const float* __restrict__ b2, const float* __restrict__ W3,
                          const float* __restrict__ b3, const float* __restrict__ bias,
                          float* __restrict__ out) {
  int n = blockIdx.x * 64 + threadIdx.x;
  if (n >= NSAMP) return;
  float s = bias[0];
  for (int f = 0; f < NFEAT; ++f) {
    float xv = X[n * NFEAT + f];
    float h1[64], h2[64];
    for (int i = 0; i < 64; ++i)
      h1[i] = fmaxf(fmaf(xv, W0[f * 64 + i], b0[f * 64 + i]), 0.f);
    for (int k = 0; k < 64; ++k) {
      float t = b1[f * 64 + k];
      for (int i = 0; i < 64; ++i) t = fmaf(h1[i], W1[f * 4096 + i * 64 + k], t);
      h2[k] = fmaxf(t, 0.f);
    }
    float c = b3[f];
    for (int k = 0; k < 32; ++k) {
      float t = b2[f * 32 + k];
      for (int i = 0; i < 64; ++i) t = fmaf(h2[i], W2[f * 2048 + i * 32 + k], t);
      c = fmaf(fmaxf(t, 0.f), W3[f * 32 + k], c);
    }
    s += c;
  }
  out[n] = s;
}

extern "C" void kernel_launch(void* const* d_in, const int* in_sizes, int n_in,
                              void* d_out, int out_size, void* d_ws, size_t ws_size,
                              hipStream_t stream) {
  const float* X    = (const float*)d_in[0];
  const float* W0   = (const float*)d_in[1];
  const float* b0   = (const float*)d_in[2];
  const float* W1   = (const float*)d_in[3];
  const float* b1   = (const float*)d_in[4];
  const float* W2   = (const float*)d_in[5];
  const float* b2   = (const float*)d_in[6];
  const float* W3   = (const float*)d_in[7];
  const float* b3   = (const float*)d_in[8];
  const float* bias = (const float*)d_in[9];
  float* out = (float*)d_out;

  const size_t W1P_BYTES  = (size_t)NFEAT * 8 * 64 * 16;   // 1 MiB
  const size_t W2P_BYTES  = (size_t)NFEAT * 4 * 64 * 16;   // 512 KiB
  const size_t XT_BYTES   = (size_t)NFEAT * NSAMP * 4;     // 4 MiB
  const size_t PART_BYTES = (size_t)NFEAT * NSAMP * 4;     // 4 MiB
  const size_t NEED = W1P_BYTES + W2P_BYTES + XT_BYTES + PART_BYTES;
  if (ws_size < NEED) {
    nam_naive<<<NSAMP / 64, 64, 0, stream>>>(X, W0, b0, W1, b1, W2, b2, W3, b3, bias, out);
    return;
  }
  char* wsb = (char*)d_ws;
  __bf16* W1p = (__bf16*)wsb;
  __bf16* W2p = (__bf16*)(wsb + W1P_BYTES);
  float*  Xt  = (float*)(wsb + W1P_BYTES + W2P_BYTES);
  float*  partb = (float*)(wsb + W1P_BYTES + W2P_BYTES + XT_BYTES);

  nam_prep<<<512, 256, 0, stream>>>(X, W1, W2, W1p, W2p, Xt);
  nam_main<<<NFEAT * 16, 256, 0, stream>>>(Xt, W0, b0, b1, b2, W3, b3,
                                           (const bf16x8*)W1p, (const bf16x8*)W2p, partb);
  nam_reduce<<<(NSAMP / 4) / 64, 256, 0, stream>>>(partb, bias, out);
}

// Round 6
// 38.459 us; speedup vs baseline: 1.0623x; 1.0623x over previous
//
#include <hip/hip_runtime.h>
#include <hip/hip_bf16.h>

typedef __bf16 bf16x8 __attribute__((ext_vector_type(8)));
typedef float  f32x4  __attribute__((ext_vector_type(4)));

#define NFEAT 128
#define NSAMP 8192
#define MT 8          // 8 M-tiles of 16 samples = 128 samples per wave

union BF8 { bf16x8 v; unsigned int u[4]; };

__device__ __forceinline__ unsigned int pk2(float lo, float hi) {
  float2 t; t.x = lo; t.y = hi;
  __hip_bfloat162 b = __float22bfloat162_rn(t);   // v_cvt_pk_bf16_f32
  union { __hip_bfloat162 b2; unsigned int u; } c;
  c.b2 = b;
  return c.u;
}

// Fragment layout (mfma_f32_16x16x32_bf16), verified rounds 1-5:
//   A: lane l holds A[row = l&15][kslot = 8*(l>>4) + j], j = 0..7
//   B: lane l holds B[kslot = 8*(l>>4) + j][col = l&15]
//   D: lane l reg r holds D[row = 4*(l>>4) + r][col = l&15]
// K-permutation pi(ks,g,j) = 32*ks + 16*(j>>2) + 4*g + (j&3) lets D-layout
// values (row = 16*mt + 4*g + r) feed the next layer's B-fragment in-lane.

// ---------------------------------------------------------------------------
// Main: 256-thread block = 4 waves; one feature x 512 samples per block.
// Coop LDS weight packing (round-4, verified). New in round 6: hoisted x
// loads + 2-way m-tile interleave for intra-wave ILP.
// ---------------------------------------------------------------------------
__global__ __launch_bounds__(256) void nam_main(
    const float* __restrict__ X,  const float* __restrict__ W0,
    const float* __restrict__ b0, const float* __restrict__ W1,
    const float* __restrict__ b1, const float* __restrict__ W2,
    const float* __restrict__ b2, const float* __restrict__ W3,
    const float* __restrict__ b3, float* __restrict__ part) {
  const int tid = threadIdx.x;
  const int l  = tid & 63;               // lane in wave
  const int w  = tid >> 6;               // wave 0..3
  const int lg = l >> 4, ls = l & 15;
  const int f  = blockIdx.x >> 4;        // one feature per block
  const int cg = blockIdx.x & 15;        // chunk group
  const int n0 = (cg * 4 + w) * 128;     // this wave's 128 samples

  __shared__ __align__(16) __bf16 w1s[8][64][8];   // 8 KiB
  __shared__ __align__(16) __bf16 w2s[4][64][8];   // 4 KiB

  // ---- per-lane layer-1 weights, pi-indexed, vectorized (pi is contiguous
  // in j within each half): w0p[ks*8 + 4*h + t] = W0[f*64 + 32ks+16h+4lg+t]
  f32x4 w0v[4], b0v[4];
#pragma unroll
  for (int ks = 0; ks < 2; ++ks)
#pragma unroll
    for (int h = 0; h < 2; ++h) {
      w0v[ks * 2 + h] = *(const f32x4*)(W0 + f * 64 + 32 * ks + 16 * h + 4 * lg);
      b0v[ks * 2 + h] = *(const f32x4*)(b0 + f * 64 + 32 * ks + 16 * h + 4 * lg);
    }
  f32x4 b1f[4], b2f[2], w3f[2];
#pragma unroll
  for (int mt = 0; mt < 4; ++mt)
    b1f[mt] = *(const f32x4*)(b1 + f * 64 + 16 * mt + 4 * lg);
#pragma unroll
  for (int mt = 0; mt < 2; ++mt)
    b2f[mt] = *(const f32x4*)(b2 + f * 32 + 16 * mt + 4 * lg);
#pragma unroll
  for (int mt = 0; mt < 2; ++mt)
    w3f[mt] = *(const f32x4*)(W3 + f * 32 + 16 * mt + 4 * lg);
  const float b3v = b3[f];

  // ---- cooperative fragment build: 768 slots over 256 threads ----
#pragma unroll
  for (int i = 0; i < 3; ++i) {
    int s = tid + 256 * i;
    int arr = (s >= 512);
    int s0 = arr ? s - 512 : s;
    int sl = s0 & 63, q = s0 >> 6;
    int slg = sl >> 4, sls = sl & 15, mt = q >> 1, ks = q & 1;
    const float* base = arr ? (W2 + f * 2048 + 16 * mt + sls)
                            : (W1 + f * 4096 + 16 * mt + sls);
    int stride = arr ? 32 : 64;
    bf16x8 v;
#pragma unroll
    for (int j = 0; j < 8; ++j) {
      int ii = 32 * ks + 16 * (j >> 2) + 4 * slg + (j & 3);
      v[j] = (__bf16)base[ii * stride];
    }
    if (arr) *(bf16x8*)&w2s[q][sl][0] = v;
    else     *(bf16x8*)&w1s[q][sl][0] = v;
  }
  __syncthreads();

  // ---- fragments to registers ----
  bf16x8 w1f[8], w2f[4];
#pragma unroll
  for (int q = 0; q < 8; ++q) w1f[q] = *(const bf16x8*)&w1s[q][l][0];
#pragma unroll
  for (int q = 0; q < 4; ++q) w2f[q] = *(const bf16x8*)&w2s[q][l][0];

  // ---- hoist all 8 x loads (independent, all in flight together) ----
  const float* xb = X + (size_t)n0 * NFEAT + f;
  float xs[MT];
#pragma unroll
  for (int m = 0; m < MT; ++m) xs[m] = xb[(16 * m + ls) * NFEAT];

  float acc[MT];
#pragma unroll
  for (int m = 0; m < MT; ++m) acc[m] = 0.f;

  // ---- main loop: 2-way interleaved m-tiles (two independent chains) ----
#pragma unroll
  for (int mm = 0; mm < MT; mm += 2) {
    // layer 1 (VALU) + packed cvt, both chains
    BF8 a1[2][2];
#pragma unroll
    for (int c = 0; c < 2; ++c) {
      const float xv = xs[mm + c];
#pragma unroll
      for (int ks = 0; ks < 2; ++ks) {
        float h[8];
#pragma unroll
        for (int j = 0; j < 8; ++j)
          h[j] = fmaxf(fmaf(xv, w0v[ks * 2 + (j >> 2)][j & 3],
                            b0v[ks * 2 + (j >> 2)][j & 3]), 0.f);
#pragma unroll
        for (int p = 0; p < 4; ++p)
          a1[c][ks].u[p] = pk2(h[2 * p], h[2 * p + 1]);
      }
    }
    // layer 2, both chains
    f32x4 h2[2][4];
#pragma unroll
    for (int c = 0; c < 2; ++c)
#pragma unroll
      for (int mt = 0; mt < 4; ++mt) {
        f32x4 cc = b1f[mt];
        cc = __builtin_amdgcn_mfma_f32_16x16x32_bf16(w1f[mt * 2 + 0], a1[c][0].v, cc, 0, 0, 0);
        cc = __builtin_amdgcn_mfma_f32_16x16x32_bf16(w1f[mt * 2 + 1], a1[c][1].v, cc, 0, 0, 0);
        h2[c][mt] = cc;
      }
    // relu + packed cvt (pi K), both chains
    BF8 bfr[2][2];
#pragma unroll
    for (int c = 0; c < 2; ++c)
#pragma unroll
      for (int ks = 0; ks < 2; ++ks)
#pragma unroll
        for (int p = 0; p < 4; ++p) {
          float lo = fmaxf(h2[c][2 * ks + (p >> 1)][(p & 1) * 2 + 0], 0.f);
          float hi = fmaxf(h2[c][2 * ks + (p >> 1)][(p & 1) * 2 + 1], 0.f);
          bfr[c][ks].u[p] = pk2(lo, hi);
        }
    // layer 3, both chains
    f32x4 h3[2][2];
#pragma unroll
    for (int c = 0; c < 2; ++c)
#pragma unroll
      for (int mt = 0; mt < 2; ++mt) {
        f32x4 cc = b2f[mt];
        cc = __builtin_amdgcn_mfma_f32_16x16x32_bf16(w2f[mt * 2 + 0], bfr[c][0].v, cc, 0, 0, 0);
        cc = __builtin_amdgcn_mfma_f32_16x16x32_bf16(w2f[mt * 2 + 1], bfr[c][1].v, cc, 0, 0, 0);
        h3[c][mt] = cc;
      }
    // epilogue, both chains (two fma chains each)
#pragma unroll
    for (int c = 0; c < 2; ++c) {
      float p0 = (lg == 0) ? b3v : 0.f, p1 = 0.f;
#pragma unroll
      for (int r = 0; r < 4; ++r) {
        p0 = fmaf(fmaxf(h3[c][0][r], 0.f), w3f[0][r], p0);
        p1 = fmaf(fmaxf(h3[c][1][r], 0.f), w3f[1][r], p1);
      }
      acc[mm + c] = p0 + p1;
    }
  }
  // ---- reduce partials across the 4 lane-groups, store ----
#pragma unroll
  for (int m = 0; m < MT; ++m) {
    float v = acc[m];
    v += __shfl_xor(v, 16, 64);
    v += __shfl_xor(v, 32, 64);
    if (l < 16) part[f * NSAMP + n0 + 16 * m + l] = v;
  }
}

// ---------------------------------------------------------------------------
// Reduce: out[n] = bias + sum_f part[f][n]. Fixed order -> deterministic.
// ---------------------------------------------------------------------------
__global__ __launch_bounds__(256) void nam_reduce(const float* __restrict__ part,
                                                  const float* __restrict__ bias,
                                                  float* __restrict__ out) {
  int tid = threadIdx.x;
  int quad = blockIdx.x * 64 + (tid & 63);
  int gs = tid >> 6;
  f32x4 s = {0.f, 0.f, 0.f, 0.f};
#pragma unroll
  for (int g = gs * 32; g < gs * 32 + 32; ++g)
    s += *(const f32x4*)(part + (size_t)g * NSAMP + quad * 4);
  __shared__ f32x4 red[256];
  red[tid] = s;
  __syncthreads();
  if (gs == 0) {
    f32x4 t = red[tid] + red[tid + 64] + red[tid + 128] + red[tid + 192];
    float bv = bias[0];
    t[0] += bv; t[1] += bv; t[2] += bv; t[3] += bv;
    *(f32x4*)(out + quad * 4) = t;
  }
}

// ---------------------------------------------------------------------------
// Fallback (only if ws too small): naive fp32, correct but slow.
// ---------------------------------------------------------------------------
__global__ void nam_naive(const float* __restrict__ X, const float* __restrict__ W0,
                          const float* __restrict__ b0, const float* __restrict__ W1,
                          const float* __restrict__ b1, const float* __restrict__ W2,
                          const float* __restrict__ b2, const float* __restrict__ W3,
                          const float* __restrict__ b3, const float* __restrict__ bias,
                          float* __restrict__ out) {
  int n = blockIdx.x * 64 + threadIdx.x;
  if (n >= NSAMP) return;
  float s = bias[0];
  for (int f = 0; f < NFEAT; ++f) {
    float xv = X[n * NFEAT + f];
    float h1[64], h2[64];
    for (int i = 0; i < 64; ++i)
      h1[i] = fmaxf(fmaf(xv, W0[f * 64 + i], b0[f * 64 + i]), 0.f);
    for (int k = 0; k < 64; ++k) {
      float t = b1[f * 64 + k];
      for (int i = 0; i < 64; ++i) t = fmaf(h1[i], W1[f * 4096 + i * 64 + k], t);
      h2[k] = fmaxf(t, 0.f);
    }
    float c = b3[f];
    for (int k = 0; k < 32; ++k) {
      float t = b2[f * 32 + k];
      for (int i = 0; i < 64; ++i) t = fmaf(h2[i], W2[f * 2048 + i * 32 + k], t);
      c = fmaf(fmaxf(t, 0.f), W3[f * 32 + k], c);
    }
    s += c;
  }
  out[n] = s;
}

extern "C" void kernel_launch(void* const* d_in, const int* in_sizes, int n_in,
                              void* d_out, int out_size, void* d_ws, size_t ws_size,
                              hipStream_t stream) {
  const float* X    = (const float*)d_in[0];
  const float* W0   = (const float*)d_in[1];
  const float* b0   = (const float*)d_in[2];
  const float* W1   = (const float*)d_in[3];
  const float* b1   = (const float*)d_in[4];
  const float* W2   = (const float*)d_in[5];
  const float* b2   = (const float*)d_in[6];
  const float* W3   = (const float*)d_in[7];
  const float* b3   = (const float*)d_in[8];
  const float* bias = (const float*)d_in[9];
  float* out = (float*)d_out;

  const size_t PART_BYTES = (size_t)NFEAT * NSAMP * 4;    // 4 MiB
  if (ws_size < PART_BYTES) {
    nam_naive<<<NSAMP / 64, 64, 0, stream>>>(X, W0, b0, W1, b1, W2, b2, W3, b3, bias, out);
    return;
  }
  float* partb = (float*)d_ws;

  nam_main<<<NFEAT * 16, 256, 0, stream>>>(X, W0, b0, W1, b1, W2, b2, W3, b3, partb);
  nam_reduce<<<(NSAMP / 4) / 64, 256, 0, stream>>>(partb, bias, out);
}

// Round 7
// 37.883 us; speedup vs baseline: 1.0784x; 1.0152x over previous
//
#include <hip/hip_runtime.h>
#include <hip/hip_bf16.h>

typedef __bf16 bf16x8 __attribute__((ext_vector_type(8)));
typedef float  f32x4  __attribute__((ext_vector_type(4)));

#define NFEAT 128
#define NSAMP 8192
#define MT 8          // 8 M-tiles of 16 samples = 128 samples per wave

union BF8 { bf16x8 v; unsigned int u[4]; };

__device__ __forceinline__ unsigned int pk2(float lo, float hi) {
  float2 t; t.x = lo; t.y = hi;
  __hip_bfloat162 b = __float22bfloat162_rn(t);   // v_cvt_pk_bf16_f32
  union { __hip_bfloat162 b2; unsigned int u; } c;
  c.b2 = b;
  return c.u;
}

// Fragment layout (mfma_f32_16x16x32_bf16), verified rounds 1-6:
//   A: lane l holds A[row = l&15][kslot = 8*(l>>4) + j], j = 0..7
//   B: lane l holds B[kslot = 8*(l>>4) + j][col = l&15]
//   D: lane l reg r holds D[row = 4*(l>>4) + r][col = l&15]
// K-permutation pi(ks,g,j) = 32*ks + 16*(j>>2) + 4*g + (j&3) lets D-layout
// values (row = 16*mt + 4*g + r) feed the next layer's B-fragment in-lane.

// ---------------------------------------------------------------------------
// Main: 256-thread block = 4 waves; one feature x 512 samples per block.
// Block-start: coop LDS staging of x (512 samples) and W1/W2 fragments.
// Inner loop: all three layers via MFMA (L1 uses [w0|b0]*[x;1] trick),
// pk2 packed converts, per-iteration partial store. Low-register design:
// launch_bounds(256,3), m-loop not unrolled.
// ---------------------------------------------------------------------------
__global__ __launch_bounds__(256, 3) void nam_main(
    const float* __restrict__ X,  const float* __restrict__ W0,
    const float* __restrict__ b0, const float* __restrict__ W1,
    const float* __restrict__ b1, const float* __restrict__ W2,
    const float* __restrict__ b2, const float* __restrict__ W3,
    const float* __restrict__ b3, float* __restrict__ part) {
  const int tid = threadIdx.x;
  const int l  = tid & 63;               // lane in wave
  const int w  = tid >> 6;               // wave 0..3
  const int lg = l >> 4, ls = l & 15;
  const int f  = blockIdx.x >> 4;        // one feature per block
  const int cg = blockIdx.x & 15;        // chunk group
  const int n0b = cg * 512;              // block's 512 samples
  const int n0w = n0b + w * 128;         // this wave's 128 samples

  __shared__ __align__(16) __bf16 w1s[8][64][8];   // 8 KiB
  __shared__ __align__(16) __bf16 w2s[4][64][8];   // 4 KiB
  __shared__ float xsh[512];                       // 2 KiB

  // ---- coop x staging: 512 scattered loads spread over 256 threads ----
#pragma unroll
  for (int i = 0; i < 2; ++i) {
    int idx = tid + 256 * i;
    xsh[idx] = X[(size_t)(n0b + idx) * NFEAT + f];
  }
  // ---- coop W1/W2 fragment build: 768 slots over 256 threads ----
#pragma unroll
  for (int i = 0; i < 3; ++i) {
    int s = tid + 256 * i;
    int arr = (s >= 512);
    int s0 = arr ? s - 512 : s;
    int sl = s0 & 63, q = s0 >> 6;
    int slg = sl >> 4, sls = sl & 15, mt = q >> 1, ks = q & 1;
    const float* base = arr ? (W2 + f * 2048 + 16 * mt + sls)
                            : (W1 + f * 4096 + 16 * mt + sls);
    int stride = arr ? 32 : 64;
    bf16x8 v;
#pragma unroll
    for (int j = 0; j < 8; ++j) {
      int ii = 32 * ks + 16 * (j >> 2) + 4 * slg + (j & 3);
      v[j] = (__bf16)base[ii * stride];
    }
    if (arr) *(bf16x8*)&w2s[q][sl][0] = v;
    else     *(bf16x8*)&w1s[q][sl][0] = v;
  }

  // ---- layer-1 A fragments: k=0 -> w0, k=1 -> b0 (lg==0 lanes only) ----
  bf16x8 w0f[4];
#pragma unroll
  for (int mt = 0; mt < 4; ++mt) {
    bf16x8 v = {};
    if (lg == 0) {
      v[0] = (__bf16)W0[f * 64 + 16 * mt + ls];
      v[1] = (__bf16)b0[f * 64 + 16 * mt + ls];
    }
    w0f[mt] = v;
  }
  // ---- bias / head fragments (D-layout) ----
  f32x4 b1f[4], b2f[2], w3f[2];
#pragma unroll
  for (int mt = 0; mt < 4; ++mt)
    b1f[mt] = *(const f32x4*)(b1 + f * 64 + 16 * mt + 4 * lg);
#pragma unroll
  for (int mt = 0; mt < 2; ++mt)
    b2f[mt] = *(const f32x4*)(b2 + f * 32 + 16 * mt + 4 * lg);
#pragma unroll
  for (int mt = 0; mt < 2; ++mt)
    w3f[mt] = *(const f32x4*)(W3 + f * 32 + 16 * mt + 4 * lg);
  const float b3v = b3[f];

  __syncthreads();

  // ---- fragments to registers (conflict-free ds_read_b128) ----
  bf16x8 w1f[8], w2f[4];
#pragma unroll
  for (int q = 0; q < 8; ++q) w1f[q] = *(const bf16x8*)&w1s[q][l][0];
#pragma unroll
  for (int q = 0; q < 4; ++q) w2f[q] = *(const bf16x8*)&w2s[q][l][0];

  const f32x4 zc = {0.f, 0.f, 0.f, 0.f};
  float* pout = part + (size_t)f * NSAMP + n0w;

#pragma unroll 1
  for (int m = 0; m < MT; ++m) {
    const float xv = xsh[w * 128 + 16 * m + ls];   // LDS broadcast read
    // ---- layer-1 B operand: [x; 1] in k-slots 0,1 (lg==0 lanes) ----
    unsigned int u0 = pk2(xv, 1.0f);
    BF8 bx; bx.u[0] = (lg == 0) ? u0 : 0u;
    bx.u[1] = 0u; bx.u[2] = 0u; bx.u[3] = 0u;
    // ---- layer 1: D[out1][sample] = w0*x + b0 ----
    f32x4 d1[4];
#pragma unroll
    for (int mt = 0; mt < 4; ++mt)
      d1[mt] = __builtin_amdgcn_mfma_f32_16x16x32_bf16(w0f[mt], bx.v, zc, 0, 0, 0);
    // ---- relu + packed cvt: d1 -> L2 B-fragments (pi K) ----
    BF8 a1[2];
#pragma unroll
    for (int ks = 0; ks < 2; ++ks)
#pragma unroll
      for (int p = 0; p < 4; ++p) {
        float lo = fmaxf(d1[2 * ks + (p >> 1)][(p & 1) * 2 + 0], 0.f);
        float hi = fmaxf(d1[2 * ks + (p >> 1)][(p & 1) * 2 + 1], 0.f);
        a1[ks].u[p] = pk2(lo, hi);
      }
    // ---- layer 2: D[out2][sample], C-init = b1 ----
    f32x4 h2[4];
#pragma unroll
    for (int mt = 0; mt < 4; ++mt) {
      f32x4 c = b1f[mt];
      c = __builtin_amdgcn_mfma_f32_16x16x32_bf16(w1f[mt * 2 + 0], a1[0].v, c, 0, 0, 0);
      c = __builtin_amdgcn_mfma_f32_16x16x32_bf16(w1f[mt * 2 + 1], a1[1].v, c, 0, 0, 0);
      h2[mt] = c;
    }
    // ---- relu + packed cvt: h2 -> L3 B-fragments (pi K) ----
    BF8 bfr[2];
#pragma unroll
    for (int ks = 0; ks < 2; ++ks)
#pragma unroll
      for (int p = 0; p < 4; ++p) {
        float lo = fmaxf(h2[2 * ks + (p >> 1)][(p & 1) * 2 + 0], 0.f);
        float hi = fmaxf(h2[2 * ks + (p >> 1)][(p & 1) * 2 + 1], 0.f);
        bfr[ks].u[p] = pk2(lo, hi);
      }
    // ---- layer 3: D[out3][sample], C-init = b2 ----
    f32x4 h3[2];
#pragma unroll
    for (int mt = 0; mt < 2; ++mt) {
      f32x4 c = b2f[mt];
      c = __builtin_amdgcn_mfma_f32_16x16x32_bf16(w2f[mt * 2 + 0], bfr[0].v, c, 0, 0, 0);
      c = __builtin_amdgcn_mfma_f32_16x16x32_bf16(w2f[mt * 2 + 1], bfr[1].v, c, 0, 0, 0);
      h3[mt] = c;
    }
    // ---- epilogue: relu, dot with w3, cross-group reduce, store ----
    float p0 = (lg == 0) ? b3v : 0.f, p1 = 0.f;
#pragma unroll
    for (int r = 0; r < 4; ++r) {
      p0 = fmaf(fmaxf(h3[0][r], 0.f), w3f[0][r], p0);
      p1 = fmaf(fmaxf(h3[1][r], 0.f), w3f[1][r], p1);
    }
    float v = p0 + p1;
    v += __shfl_xor(v, 16, 64);
    v += __shfl_xor(v, 32, 64);
    if (l < 16) pout[16 * m + l] = v;
  }
}

// ---------------------------------------------------------------------------
// Reduce: out[n] = bias + sum_f part[f][n]. Fixed order -> deterministic.
// ---------------------------------------------------------------------------
__global__ __launch_bounds__(256) void nam_reduce(const float* __restrict__ part,
                                                  const float* __restrict__ bias,
                                                  float* __restrict__ out) {
  int tid = threadIdx.x;
  int quad = blockIdx.x * 64 + (tid & 63);
  int gs = tid >> 6;
  f32x4 s = {0.f, 0.f, 0.f, 0.f};
#pragma unroll
  for (int g = gs * 32; g < gs * 32 + 32; ++g)
    s += *(const f32x4*)(part + (size_t)g * NSAMP + quad * 4);
  __shared__ f32x4 red[256];
  red[tid] = s;
  __syncthreads();
  if (gs == 0) {
    f32x4 t = red[tid] + red[tid + 64] + red[tid + 128] + red[tid + 192];
    float bv = bias[0];
    t[0] += bv; t[1] += bv; t[2] += bv; t[3] += bv;
    *(f32x4*)(out + quad * 4) = t;
  }
}

// ---------------------------------------------------------------------------
// Fallback (only if ws too small): naive fp32, correct but slow.
// ---------------------------------------------------------------------------
__global__ void nam_naive(const float* __restrict__ X, const float* __restrict__ W0,
                          const float* __restrict__ b0, const float* __restrict__ W1,
                          const float* __restrict__ b1, const float* __restrict__ W2,
                          const float* __restrict__ b2, const float* __restrict__ W3,
                          const float* __restrict__ b3, const float* __restrict__ bias,
                          float* __restrict__ out) {
  int n = blockIdx.x * 64 + threadIdx.x;
  if (n >= NSAMP) return;
  float s = bias[0];
  for (int f = 0; f < NFEAT; ++f) {
    float xv = X[n * NFEAT + f];
    float h1[64], h2[64];
    for (int i = 0; i < 64; ++i)
      h1[i] = fmaxf(fmaf(xv, W0[f * 64 + i], b0[f * 64 + i]), 0.f);
    for (int k = 0; k < 64; ++k) {
      float t = b1[f * 64 + k];
      for (int i = 0; i < 64; ++i) t = fmaf(h1[i], W1[f * 4096 + i * 64 + k], t);
      h2[k] = fmaxf(t, 0.f);
    }
    float c = b3[f];
    for (int k = 0; k < 32; ++k) {
      float t = b2[f * 32 + k];
      for (int i = 0; i < 64; ++i) t = fmaf(h2[i], W2[f * 2048 + i * 32 + k], t);
      c = fmaf(fmaxf(t, 0.f), W3[f * 32 + k], c);
    }
    s += c;
  }
  out[n] = s;
}

extern "C" void kernel_launch(void* const* d_in, const int* in_sizes, int n_in,
                              void* d_out, int out_size, void* d_ws, size_t ws_size,
                              hipStream_t stream) {
  const float* X    = (const float*)d_in[0];
  const float* W0   = (const float*)d_in[1];
  const float* b0   = (const float*)d_in[2];
  const float* W1   = (const float*)d_in[3];
  const float* b1   = (const float*)d_in[4];
  const float* W2   = (const float*)d_in[5];
  const float* b2   = (const float*)d_in[6];
  const float* W3   = (const float*)d_in[7];
  const float* b3   = (const float*)d_in[8];
  const float* bias = (const float*)d_in[9];
  float* out = (float*)d_out;

  const size_t PART_BYTES = (size_t)NFEAT * NSAMP * 4;    // 4 MiB
  if (ws_size < PART_BYTES) {
    nam_naive<<<NSAMP / 64, 64, 0, stream>>>(X, W0, b0, W1, b1, W2, b2, W3, b3, bias, out);
    return;
  }
  float* partb = (float*)d_ws;

  nam_main<<<NFEAT * 16, 256, 0, stream>>>(X, W0, b0, W1, b1, W2, b2, W3, b3, partb);
  nam_reduce<<<(NSAMP / 4) / 64, 256, 0, stream>>>(partb, bias, out);
}